// Round 12
// baseline (393.245 us; speedup 1.0000x reference)
//
#include <hip/hip_runtime.h>
#include <hip/hip_bf16.h>
#include <math.h>

// Problem constants
#define B_   2
#define T_   2048
#define M_   2048
#define D_   384
#define H_   4
#define DH_  96
#define NM_  8
#define DF_  1536
#define R_   16
#define NR_  4096   // B*T = B*M rows
#define SPL  4      // attention key-splits

typedef unsigned short u16;
typedef u16    u16x8  __attribute__((ext_vector_type(8)));
typedef u16    u16x4  __attribute__((ext_vector_type(4)));
typedef __bf16 bf16x8 __attribute__((ext_vector_type(8)));
typedef float  f32x4  __attribute__((ext_vector_type(4)));

union V8 { u16x8 u; bf16x8 b; };
__device__ __forceinline__ bf16x8 as_bf(u16x8 x) { V8 v; v.u = x; return v.b; }

__device__ __forceinline__ u16 f2bf(float f) {
    unsigned u = __float_as_uint(f);
    unsigned r = (u + 0x7fffu + ((u >> 16) & 1u)) >> 16;
    return (u16)r;
}
__device__ __forceinline__ float bf2f(u16 u) {
    return __uint_as_float(((unsigned)u) << 16);
}

// async global->LDS: 16B per lane, dest = wave-uniform base + lane*16
__device__ __forceinline__ void load16(const u16* g, u16* l) {
    __builtin_amdgcn_global_load_lds(
        (const __attribute__((address_space(1))) void*)g,
        (__attribute__((address_space(3))) void*)l, 16, 0, 0);
}

// ---------------- fused setup: weight converts + bias pack + gates ----------------
__global__ __launch_bounds__(256)
void setup_kernel(const float* cWq, const float* cWk, const float* cWv, const float* cWo,
                  const float* sWq, const float* sWk, const float* sWv, const float* sWo,
                  const float* f1W, const float* f2W, const float* adA, const float* adB,
                  const float* mem,
                  u16* Wqkv_c, u16* Wco, u16* Wqkv_s, u16* Wso,
                  u16* Wf1, u16* Wf2, u16* WadA, u16* WadB, u16* memb,
                  const float* cbq, const float* cbk, const float* cbv,
                  const float* sbq, const float* sbk, const float* sbv,
                  float* bqkv_c, float* bqkv_s,
                  const float* mc, const float* gW, const float* gb, float* gates) {
    int seg = blockIdx.y;
    if (seg == 13) {
        for (int i = blockIdx.x * 256 + threadIdx.x; i < 2312; i += gridDim.x * 256) {
            if (i < 1152) {
                bqkv_c[i] = (i < 384) ? cbq[i] : (i < 768 ? cbk[i - 384] : cbv[i - 768]);
            } else if (i < 2304) {
                int j = i - 1152;
                bqkv_s[j] = (j < 384) ? sbq[j] : (j < 768 ? sbk[j - 384] : sbv[j - 768]);
            } else {
                int k = i - 2304;  // 0..7
                int b = k / H_, h = k % H_;
                float s = gb[h];
                for (int n = 0; n < NM_; n++)
                    s += mc[b * NM_ + n] * gW[h * NM_ + n];
                gates[k] = 1.f / (1.f + __expf(-s));
            }
        }
        return;
    }
    const float* s; u16* d; int n;
    switch (seg) {
        case 0:  s = cWq; d = Wqkv_c;           n = 147456; break;
        case 1:  s = cWk; d = Wqkv_c + 147456;  n = 147456; break;
        case 2:  s = cWv; d = Wqkv_c + 294912;  n = 147456; break;
        case 3:  s = cWo; d = Wco;              n = 147456; break;
        case 4:  s = sWq; d = Wqkv_s;           n = 147456; break;
        case 5:  s = sWk; d = Wqkv_s + 147456;  n = 147456; break;
        case 6:  s = sWv; d = Wqkv_s + 294912;  n = 147456; break;
        case 7:  s = sWo; d = Wso;              n = 147456; break;
        case 8:  s = f1W; d = Wf1;              n = 589824; break;
        case 9:  s = f2W; d = Wf2;              n = 589824; break;
        case 10: s = adA; d = WadA;             n = 24576;  break;
        case 11: s = adB; d = WadB;             n = 24576;  break;
        default: s = mem; d = memb;             n = 1572864; break;
    }
    for (int i = blockIdx.x * 256 + threadIdx.x; i < n; i += gridDim.x * 256)
        d[i] = f2bf(s[i]);
}

// ---------------- GEMM with fused LayerNorm on A (64-row block, K=384) ----------------
// A = LN(Xf) for bn < aswitch, else bf16 passthrough A1 (no LN).
// W staged by DMA (dbuf); A staged by VALU (dbuf) with LN applied.
// VT: cols >= vtbase written transposed into Vt. LORAA: block col NC/64 computes Tl.
template<int ACT, bool OBF, bool VT, bool LORAA>
__global__ __launch_bounds__(256)
void gemm_ln(const float* __restrict__ Xf, const u16* __restrict__ A1, int aswitch,
             const float* __restrict__ lng, const float* __restrict__ lnb,
             const u16* __restrict__ W, const float* __restrict__ bias,
             void* __restrict__ Cout, int NC,
             u16* __restrict__ Vt, int vtbase,
             const u16* __restrict__ adW, u16* __restrict__ TlOut,
             const int* __restrict__ aidx) {
    const int K = 384;
    __shared__ __align__(16) u16 SA[2][4096];
    __shared__ __align__(16) u16 SW[2][4096];
    __shared__ float smu[64], sr[64];
    __shared__ float slg[384], slb[384];
    int tid = threadIdx.x, w = tid >> 6, lane = tid & 63;
    int l15 = lane & 15, quad = lane >> 4;
    int bm = blockIdx.y * 64, bn = blockIdx.x * 64;
    bool loraBlk = LORAA && (bn >= NC);
    bool pass = (bn >= aswitch);

    const u16* Wb = W;
    if (LORAA && loraBlk) Wb = adW + (long)aidx[0] * 6144;

    // W DMA descriptors: region r = i*4+w (8 regions: nt = r>>1, kc = r&1)
    const u16* WG[2]; int WO[2];
    #pragma unroll
    for (int i = 0; i < 2; i++) {
        int r = i * 4 + w, nt = r >> 1, kc = r & 1;
        int wrow = (LORAA && loraBlk) ? ((nt * 16 + l15) & 15) : (bn + nt * 16 + l15);
        WG[i] = Wb + (long)wrow * K + kc * 32 + quad * 8;
        WO[i] = r * 512;
    }

    // LN stats + params (skipped for passthrough blocks; no barrier inside)
    if (!pass) {
        int row = tid >> 2, q4 = tid & 3;
        const float* src = Xf + (long)(bm + row) * K + q4 * 96;
        float s = 0.f, s2 = 0.f;
        #pragma unroll
        for (int i = 0; i < 24; i++) {
            f32x4 v = *(const f32x4*)(src + i * 4);
            #pragma unroll
            for (int e = 0; e < 4; e++) { s += v[e]; s2 += v[e] * v[e]; }
        }
        s  += __shfl_xor(s, 1);  s  += __shfl_xor(s, 2);
        s2 += __shfl_xor(s2, 1); s2 += __shfl_xor(s2, 2);
        if (q4 == 0) {
            float mu = s * (1.f / 384.f);
            float var = s2 * (1.f / 384.f) - mu * mu;
            smu[row] = mu;
            sr[row] = rsqrtf(var + 1e-5f);
        }
        if (tid < 192) {
            f32x4 g4 = *(const f32x4*)(lng + tid * 2);
            // load 2 floats each for g and b (384 floats over 192 threads)
            slg[tid * 2] = g4[0]; slg[tid * 2 + 1] = g4[1];
            f32x4 b4 = *(const f32x4*)(lnb + tid * 2);
            slb[tid * 2] = b4[0]; slb[tid * 2 + 1] = b4[1];
        }
    }
    // prologue DMA W(0)
    #pragma unroll
    for (int i = 0; i < 2; i++) load16(WG[i], &SW[0][0] + WO[i]);
    __syncthreads();   // stats visible

    // stage A(0)
    {
        int row = tid & 63;
        #pragma unroll
        for (int i = 0; i < 2; i++) {
            int kg = (tid >> 6) + i * 4;
            int k = kg * 8;
            u16x8 hv;
            if (pass) {
                hv = *(const u16x8*)(A1 + (long)(bm + row) * K + k);
            } else {
                const float* src = Xf + (long)(bm + row) * K + k;
                float mu = smu[row], r = sr[row];
                #pragma unroll
                for (int e = 0; e < 8; e++)
                    hv[e] = f2bf((src[e] - mu) * r * slg[k + e] + slb[k + e]);
            }
            *(u16x8*)(&SA[0][0] + ((row >> 4) * 2 + (kg >> 2)) * 512 + (kg & 3) * 128 + (row & 15) * 8) = hv;
        }
    }

    f32x4 acc[2][2];
    #pragma unroll
    for (int s = 0; s < 2; s++)
        #pragma unroll
        for (int j = 0; j < 2; j++) acc[s][j] = (f32x4){0.f, 0.f, 0.f, 0.f};

    for (int it = 0; it < 6; it++) {
        __syncthreads();   // A(cur) visible, W(cur) DMA drained, buffers free
        int cur = it & 1, nxt = cur ^ 1;
        if (it + 1 < 6) {
            int k0 = (it + 1) * 64;
            #pragma unroll
            for (int i = 0; i < 2; i++) load16(WG[i] + k0, &SW[nxt][0] + WO[i]);
            int row = tid & 63;
            #pragma unroll
            for (int i = 0; i < 2; i++) {
                int kg = (tid >> 6) + i * 4;
                int k = k0 + kg * 8;
                u16x8 hv;
                if (pass) {
                    hv = *(const u16x8*)(A1 + (long)(bm + row) * K + k);
                } else {
                    const float* src = Xf + (long)(bm + row) * K + k;
                    float mu = smu[row], r = sr[row];
                    #pragma unroll
                    for (int e = 0; e < 8; e++)
                        hv[e] = f2bf((src[e] - mu) * r * slg[k + e] + slb[k + e]);
                }
                *(u16x8*)(&SA[nxt][0] + ((row >> 4) * 2 + (kg >> 2)) * 512 + (kg & 3) * 128 + (row & 15) * 8) = hv;
            }
        }
        #pragma unroll
        for (int kc = 0; kc < 2; kc++) {
            u16x8 af[2], bfv[2];
            #pragma unroll
            for (int s = 0; s < 2; s++)
                af[s] = *(const u16x8*)(&SA[cur][0] + (((w & 1) * 2 + s) * 2 + kc) * 512 + lane * 8);
            #pragma unroll
            for (int j = 0; j < 2; j++)
                bfv[j] = *(const u16x8*)(&SW[cur][0] + ((((w >> 1) * 2 + j)) * 2 + kc) * 512 + lane * 8);
            #pragma unroll
            for (int s = 0; s < 2; s++)
                #pragma unroll
                for (int j = 0; j < 2; j++)
                    acc[s][j] = __builtin_amdgcn_mfma_f32_16x16x32_bf16(
                        as_bf(af[s]), as_bf(bfv[j]), acc[s][j], 0, 0, 0);
        }
    }

    #pragma unroll
    for (int mi = 0; mi < 2; mi++) {
        int rowb = bm + ((w & 1) * 2 + mi) * 16 + quad * 4;
        #pragma unroll
        for (int nj = 0; nj < 2; nj++) {
            int coll = ((w >> 1) * 2 + nj) * 16 + l15;
            int col = bn + coll;
            if (LORAA && loraBlk) {
                if (coll < 16) {
                    #pragma unroll
                    for (int r = 0; r < 4; r++)
                        TlOut[(long)(rowb + r) * 16 + coll] = f2bf(acc[mi][nj][r]);
                }
            } else {
                float bv = bias ? bias[col] : 0.f;
                if (VT && col >= vtbase) {
                    int vc = col - vtbase;
                    int b = rowb >> 11, rowl = rowb & 2047;
                    u16x4 ov;
                    #pragma unroll
                    for (int r = 0; r < 4; r++) ov[r] = f2bf(acc[mi][nj][r] + bv);
                    *(u16x4*)(Vt + ((long)b * 384 + vc) * 2048 + rowl) = ov;
                } else {
                    #pragma unroll
                    for (int r = 0; r < 4; r++) {
                        float v = acc[mi][nj][r] + bv;
                        if (ACT == 1) v = 0.5f * v * (1.f + erff(v * 0.70710678118654752f));
                        ((u16*)Cout)[(long)(rowb + r) * NC + col] = f2bf(v);
                    }
                }
            }
        }
    }
}

// ---------------- O-projection GEMM with fused split-combine on A (32-row block) ----------------
// A[row][k] = (gate(b,h)/L[row,h]) * sum_s Po[s][row][k];  C = A @ W^T + bias + res (fp32 out)
__global__ __launch_bounds__(256)
void gemm_comb(const u16* __restrict__ Po, const float* __restrict__ Pl,
               const float* __restrict__ gates,
               const u16* __restrict__ W, const float* __restrict__ bias,
               const float* __restrict__ res, float* __restrict__ Cout) {
    const int K = 384, NC = 384;
    __shared__ __align__(16) u16 SA[2][2048];
    __shared__ __align__(16) u16 SW[2][4096];
    __shared__ float ssc[32][4];
    int tid = threadIdx.x, w = tid >> 6, lane = tid & 63;
    int l15 = lane & 15, quad = lane >> 4;
    int bm = blockIdx.y * 32, bn = blockIdx.x * 64;

    const u16* WG[2]; int WO[2];
    #pragma unroll
    for (int i = 0; i < 2; i++) {
        int r = i * 4 + w, nt = r >> 1, kc = r & 1;
        WG[i] = W + (long)(bn + nt * 16 + l15) * K + kc * 32 + quad * 8;
        WO[i] = r * 512;
    }

    if (tid < 128) {
        int row = tid >> 2, h = tid & 3;
        int grow = bm + row, b = grow >> 11, tl = grow & 2047;
        float L = 0.f;
        #pragma unroll
        for (int s = 0; s < SPL; s++) L += Pl[(long)(s * 8 + b * 4 + h) * 2048 + tl];
        float g = gates ? gates[b * 4 + h] : 1.f;
        ssc[row][h] = g / L;
    }
    #pragma unroll
    for (int i = 0; i < 2; i++) load16(WG[i], &SW[0][0] + WO[i]);
    __syncthreads();

    int row = tid & 31, kg = tid >> 5;   // one group per thread
    int grow = bm + row, b = grow >> 11, tl = grow & 2047;
    // stage A(0)
    {
        int k = kg * 8;
        int h = k / 96, d = k - h * 96;
        const u16* base = Po + ((long)(b * 4 + h) * 2048 + tl) * 96 + d;
        float a[8] = {0.f, 0.f, 0.f, 0.f, 0.f, 0.f, 0.f, 0.f};
        #pragma unroll
        for (int s = 0; s < SPL; s++) {
            u16x8 v = *(const u16x8*)(base + (long)s * 1572864);
            #pragma unroll
            for (int e = 0; e < 8; e++) a[e] += bf2f(v[e]);
        }
        float sc = ssc[row][h];
        u16x8 hv;
        #pragma unroll
        for (int e = 0; e < 8; e++) hv[e] = f2bf(a[e] * sc);
        *(u16x8*)(&SA[0][0] + ((row >> 4) * 2 + (kg >> 2)) * 512 + (kg & 3) * 128 + (row & 15) * 8) = hv;
    }

    f32x4 acc[2];
    acc[0] = (f32x4){0.f, 0.f, 0.f, 0.f};
    acc[1] = (f32x4){0.f, 0.f, 0.f, 0.f};

    for (int it = 0; it < 6; it++) {
        __syncthreads();
        int cur = it & 1, nxt = cur ^ 1;
        if (it + 1 < 6) {
            int k0 = (it + 1) * 64;
            #pragma unroll
            for (int i = 0; i < 2; i++) load16(WG[i] + k0, &SW[nxt][0] + WO[i]);
            int k = k0 + kg * 8;
            int h = k / 96, d = k - h * 96;
            const u16* base = Po + ((long)(b * 4 + h) * 2048 + tl) * 96 + d;
            float a[8] = {0.f, 0.f, 0.f, 0.f, 0.f, 0.f, 0.f, 0.f};
            #pragma unroll
            for (int s = 0; s < SPL; s++) {
                u16x8 v = *(const u16x8*)(base + (long)s * 1572864);
                #pragma unroll
                for (int e = 0; e < 8; e++) a[e] += bf2f(v[e]);
            }
            float sc = ssc[row][h];
            u16x8 hv;
            #pragma unroll
            for (int e = 0; e < 8; e++) hv[e] = f2bf(a[e] * sc);
            *(u16x8*)(&SA[nxt][0] + ((row >> 4) * 2 + (kg >> 2)) * 512 + (kg & 3) * 128 + (row & 15) * 8) = hv;
        }
        #pragma unroll
        for (int kc = 0; kc < 2; kc++) {
            u16x8 af, bfv[2];
            af = *(const u16x8*)(&SA[cur][0] + ((w & 1) * 2 + kc) * 512 + lane * 8);
            #pragma unroll
            for (int j = 0; j < 2; j++)
                bfv[j] = *(const u16x8*)(&SW[cur][0] + (((w >> 1) * 2 + j) * 2 + kc) * 512 + lane * 8);
            #pragma unroll
            for (int j = 0; j < 2; j++)
                acc[j] = __builtin_amdgcn_mfma_f32_16x16x32_bf16(
                    as_bf(af), as_bf(bfv[j]), acc[j], 0, 0, 0);
        }
    }

    int rowb = bm + (w & 1) * 16 + quad * 4;
    #pragma unroll
    for (int nj = 0; nj < 2; nj++) {
        int col = bn + ((w >> 1) * 2 + nj) * 16 + l15;
        float bv = bias[col];
        #pragma unroll
        for (int r = 0; r < 4; r++) {
            long idx = (long)(rowb + r) * NC + col;
            Cout[idx] = acc[nj][r] + bv + res[idx];
        }
    }
}

// ---------------- unified pipelined MFMA GEMM (f2 only): MT=1, LORA epilogue ----------------
__global__ __launch_bounds__(256)
void gemm_f2(const u16* __restrict__ A, const u16* __restrict__ W,
             const float* __restrict__ bias, const float* __restrict__ res,
             float* __restrict__ Cout, int NC, int K,
             const u16* __restrict__ Tl, const u16* __restrict__ adW,
             const int* __restrict__ aidx) {
    constexpr int HALF = 12 * 512;
    __shared__ __align__(16) u16 S[2 * HALF];
    int tid = threadIdx.x, w = tid >> 6, lane = tid & 63;
    int l15 = lane & 15, quad = lane >> 4;
    int bm = blockIdx.y * 32, bn = blockIdx.x * 64;

    const u16* GP[3]; int LO[3];
    #pragma unroll
    for (int i = 0; i < 3; i++) {
        int r = i * 4 + w;
        const u16* src;
        if (r < 4) {
            int mt = r >> 1, kc = r & 1;
            src = A + (long)(bm + mt * 16 + l15) * K + kc * 32 + quad * 8;
        } else {
            int rw = r - 4, nt = rw >> 1, kc = rw & 1;
            src = W + (long)(bn + nt * 16 + l15) * K + kc * 32 + quad * 8;
        }
        GP[i] = src;
        LO[i] = r * 512;
    }

    f32x4 acc[2];
    acc[0] = (f32x4){0.f, 0.f, 0.f, 0.f};
    acc[1] = (f32x4){0.f, 0.f, 0.f, 0.f};

    int niter = K >> 6;
    #pragma unroll
    for (int i = 0; i < 3; i++) load16(GP[i], S + LO[i]);

    for (int it = 0; it < niter; it++) {
        __syncthreads();
        int cur = (it & 1) * HALF, nxt = HALF - cur;
        if (it + 1 < niter) {
            int k = (it + 1) << 6;
            #pragma unroll
            for (int i = 0; i < 3; i++) load16(GP[i] + k, S + nxt + LO[i]);
        }
        #pragma unroll
        for (int kc = 0; kc < 2; kc++) {
            u16x8 af, bfv[2];
            af = *(const u16x8*)(S + cur + ((w & 1) * 2 + kc) * 512 + lane * 8);
            #pragma unroll
            for (int j = 0; j < 2; j++)
                bfv[j] = *(const u16x8*)(S + cur + (4 + ((w >> 1) * 2 + j) * 2 + kc) * 512 + lane * 8);
            #pragma unroll
            for (int j = 0; j < 2; j++)
                acc[j] = __builtin_amdgcn_mfma_f32_16x16x32_bf16(
                    as_bf(af), as_bf(bfv[j]), acc[j], 0, 0, 0);
        }
    }

    // LoRA-B: acc += Tl @ adW[aidx]^T (K=16 zero-padded)
    {
        long ao = (long)aidx[0] * 6144;
        u16x8 tlf = {0, 0, 0, 0, 0, 0, 0, 0};
        u16x8 adf[2] = {{0, 0, 0, 0, 0, 0, 0, 0}, {0, 0, 0, 0, 0, 0, 0, 0}};
        if (quad < 2) {
            tlf = *(const u16x8*)(Tl + (long)(bm + (w & 1) * 16 + l15) * 16 + quad * 8);
            #pragma unroll
            for (int j = 0; j < 2; j++)
                adf[j] = *(const u16x8*)(adW + ao + (long)(bn + ((w >> 1) * 2 + j) * 16 + l15) * 16 + quad * 8);
        }
        #pragma unroll
        for (int j = 0; j < 2; j++)
            acc[j] = __builtin_amdgcn_mfma_f32_16x16x32_bf16(
                as_bf(tlf), as_bf(adf[j]), acc[j], 0, 0, 0);
    }

    int rowb = bm + (w & 1) * 16 + quad * 4;
    #pragma unroll
    for (int nj = 0; nj < 2; nj++) {
        int col = bn + ((w >> 1) * 2 + nj) * 16 + l15;
        float bv = bias[col];
        #pragma unroll
        for (int r = 0; r < 4; r++) {
            long idx = (long)(rowb + r) * NC + col;
            Cout[idx] = acc[nj][r] + bv + res[idx];
        }
    }
}

// ---------------- Flash attention (R9 config): 32 Q-rows/wave, K/V dbuf, key-split x4 ----------------
__global__ __launch_bounds__(256)
void attn_mfma(const u16* __restrict__ Qg, int qs,
               const u16* __restrict__ Kg, int ks,
               const u16* __restrict__ Vt,
               u16* __restrict__ Po, float* __restrict__ Pl) {
    __shared__ __align__(16) u16 Ks[2][6144];
    __shared__ __align__(16) u16 Vs[2][6144];
    __shared__ __align__(16) u16 Ps[4][2][1088];
    const float SCALE = 0.10206207261596575f;  // 1/sqrt(96)

    int tid = threadIdx.x, wv = tid >> 6, lane = tid & 63;
    int l15 = lane & 15, quad = lane >> 4;
    int bh = blockIdx.y, b = bh >> 2, h = bh & 3;
    int split = blockIdx.z;
    int q0 = blockIdx.x * 128 + wv * 32;

    const u16* Qb = Qg + (long)(b * 2048 + q0) * qs + h * 96;
    const u16* Kb = Kg + (long)(b * 2048 + split * 512) * ks + h * 96;
    const u16* Vb = Vt + (long)(b * 384 + h * 96) * 2048 + split * 512;

    u16x8 qf[2][3];
    #pragma unroll
    for (int g = 0; g < 2; g++)
        #pragma unroll
        for (int t = 0; t < 3; t++)
            qf[g][t] = *(const u16x8*)(Qb + (long)(g * 16 + l15) * qs + t * 32 + quad * 8);

    f32x4 o[2][6];
    #pragma unroll
    for (int g = 0; g < 2; g++)
        #pragma unroll
        for (int i = 0; i < 6; i++) o[g][i] = (f32x4){0.f, 0.f, 0.f, 0.f};
    float rs[2][4] = {{0.f, 0.f, 0.f, 0.f}, {0.f, 0.f, 0.f, 0.f}};

    const u16* KgI[3]; int KlO[3]; const u16* VgI[3]; int VlO[3];
    #pragma unroll
    for (int i = 0; i < 3; i++) {
        int r = i * 4 + wv;
        int ksub = r & 3, kst = r >> 2;
        KgI[i] = Kb + (long)(ksub * 16 + l15) * ks + kst * 32 + quad * 8;
        KlO[i] = (ksub * 3 + kst) * 512;
        int nt = r >> 1, t2 = r & 1;
        VgI[i] = Vb + (long)(nt * 16 + l15) * 2048 + t2 * 32 + quad * 8;
        VlO[i] = r * 512;
    }

    #pragma unroll
    for (int i = 0; i < 3; i++) {
        load16(KgI[i], &Ks[0][0] + KlO[i]);
        load16(VgI[i], &Vs[0][0] + VlO[i]);
    }

    for (int it = 0; it < 8; it++) {
        __syncthreads();
        int cur = it & 1, nxt = cur ^ 1;
        if (it + 1 < 8) {
            int j = (it + 1) * 64;
            #pragma unroll
            for (int i = 0; i < 3; i++) {
                load16(KgI[i] + (long)j * ks, &Ks[nxt][0] + KlO[i]);
                load16(VgI[i] + j, &Vs[nxt][0] + VlO[i]);
            }
        }

        f32x4 sc[2][4];
        #pragma unroll
        for (int g = 0; g < 2; g++)
            #pragma unroll
            for (int s = 0; s < 4; s++) sc[g][s] = (f32x4){0.f, 0.f, 0.f, 0.f};
        #pragma unroll
        for (int s = 0; s < 4; s++)
            #pragma unroll
            for (int t = 0; t < 3; t++) {
                u16x8 kf = *(const u16x8*)(&Ks[cur][0] + (s * 3 + t) * 512 + lane * 8);
                sc[0][s] = __builtin_amdgcn_mfma_f32_16x16x32_bf16(as_bf(qf[0][t]), as_bf(kf), sc[0][s], 0, 0, 0);
                sc[1][s] = __builtin_amdgcn_mfma_f32_16x16x32_bf16(as_bf(qf[1][t]), as_bf(kf), sc[1][s], 0, 0, 0);
            }

        #pragma unroll
        for (int g = 0; g < 2; g++)
            #pragma unroll
            for (int s = 0; s < 4; s++) {
                int base = (s >> 1) * 544 + ((((s & 1) << 1) | (l15 >> 3))) * 136 + (l15 & 7);
                #pragma unroll
                for (int r = 0; r < 4; r++) {
                    float p = __expf(sc[g][s][r] * SCALE);
                    rs[g][r] += p;
                    Ps[wv][g][base + (quad * 4 + r) * 8] = f2bf(p);
                }
            }

        #pragma unroll
        for (int t2 = 0; t2 < 2; t2++) {
            u16x8 pf0 = *(const u16x8*)(&Ps[wv][0][0] + t2 * 544 + quad * 136 + l15 * 8);
            u16x8 pf1 = *(const u16x8*)(&Ps[wv][1][0] + t2 * 544 + quad * 136 + l15 * 8);
            #pragma unroll
            for (int nt = 0; nt < 6; nt++) {
                u16x8 vf = *(const u16x8*)(&Vs[cur][0] + (nt * 2 + t2) * 512 + lane * 8);
                o[0][nt] = __builtin_amdgcn_mfma_f32_16x16x32_bf16(as_bf(pf0), as_bf(vf), o[0][nt], 0, 0, 0);
                o[1][nt] = __builtin_amdgcn_mfma_f32_16x16x32_bf16(as_bf(pf1), as_bf(vf), o[1][nt], 0, 0, 0);
            }
        }
    }

    #pragma unroll
    for (int off = 1; off < 16; off <<= 1)
        #pragma unroll
        for (int g = 0; g < 2; g++)
            #pragma unroll
            for (int r = 0; r < 4; r++) rs[g][r] += __shfl_xor(rs[g][r], off);

    #pragma unroll
    for (int g = 0; g < 2; g++) {
        u16* Pob = Po + ((long)(split * 8 + bh) * 2048 + q0 + g * 16) * 96;
        #pragma unroll
        for (int nt = 0; nt < 6; nt++)
            #pragma unroll
            for (int r = 0; r < 4; r++)
                Pob[(long)(quad * 4 + r) * 96 + nt * 16 + l15] = f2bf(o[g][nt][r]);
        if (l15 == 0) {
            long mb = (long)(split * 8 + bh) * 2048 + q0 + g * 16 + quad * 4;
            #pragma unroll
            for (int r = 0; r < 4; r++) Pl[mb + r] = rs[g][r];
        }
    }
}

// ---------------- Launch ----------------
extern "C" void kernel_launch(void* const* d_in, const int* in_sizes, int n_in,
                              void* d_out, int out_size, void* d_ws, size_t ws_size,
                              hipStream_t stream) {
    const float* x    = (const float*)d_in[0];
    const float* mem  = (const float*)d_in[1];
    const float* mc   = (const float*)d_in[2];
    const int*   aidx = (const int*)d_in[3];
    const float* cWq = (const float*)d_in[4],  *cbq = (const float*)d_in[5];
    const float* cWk = (const float*)d_in[6],  *cbk = (const float*)d_in[7];
    const float* cWv = (const float*)d_in[8],  *cbv = (const float*)d_in[9];
    const float* cWo = (const float*)d_in[10], *cbo = (const float*)d_in[11];
    const float* sWq = (const float*)d_in[12], *sbq = (const float*)d_in[13];
    const float* sWk = (const float*)d_in[14], *sbk = (const float*)d_in[15];
    const float* sWv = (const float*)d_in[16], *sbv = (const float*)d_in[17];
    const float* sWo = (const float*)d_in[18], *sbo = (const float*)d_in[19];
    const float* gW  = (const float*)d_in[20], *gb  = (const float*)d_in[21];
    const float* f1W = (const float*)d_in[22], *f1b = (const float*)d_in[23];
    const float* f2W = (const float*)d_in[24], *f2b = (const float*)d_in[25];
    const float* adA = (const float*)d_in[26], *adB = (const float*)d_in[27];
    const float* ln1g = (const float*)d_in[28], *ln1b = (const float*)d_in[29];
    const float* ln2g = (const float*)d_in[30], *ln2b = (const float*)d_in[31];
    const float* ln3g = (const float*)d_in[32], *ln3b = (const float*)d_in[33];

    // ---- workspace layout ----
    u16* p = (u16*)d_ws;
    u16* bufQKV = p; p += (size_t)NR_ * 1152;
    u16* Vt     = p; p += (size_t)B_ * 384 * 2048;
    u16* F      = p; p += (size_t)NR_ * 1536;
    u16* Tl     = p; p += (size_t)NR_ * 16;
    u16* memb   = p; p += (size_t)NR_ * 384;
    u16* Wqkv_c = p; p += 442368;
    u16* Wco    = p; p += 147456;
    u16* Wqkv_s = p; p += 442368;
    u16* Wso    = p; p += 147456;
    u16* Wf1    = p; p += 589824;
    u16* Wf2    = p; p += 589824;
    u16* WadA   = p; p += 24576;
    u16* WadB   = p; p += 24576;
    u16* Po     = p; p += (size_t)SPL * 8 * 2048 * 96;
    float* fp = (float*)(((size_t)p + 3) & ~(size_t)3);
    float* X1 = fp;     fp += (size_t)NR_ * 384;
    float* X2 = fp;     fp += (size_t)NR_ * 384;
    float* Pl = fp;     fp += (size_t)SPL * 8 * 2048;
    float* bqkv_c = fp; fp += 1152;
    float* bqkv_s = fp; fp += 1152;
    float* gbuf   = fp; fp += 8;

    // ---- fused setup ----
    setup_kernel<<<dim3(96, 14), 256, 0, stream>>>(
        cWq, cWk, cWv, cWo, sWq, sWk, sWv, sWo, f1W, f2W, adA, adB, mem,
        Wqkv_c, Wco, Wqkv_s, Wso, Wf1, Wf2, WadA, WadB, memb,
        cbq, cbk, cbv, sbq, sbk, sbv, bqkv_c, bqkv_s, mc, gW, gb, gbuf);

    // --- cross-attention: LN1 fused into QKV projection (Q from LN(x), K/V from memb) ---
    gemm_ln<0, true, true, false><<<dim3(18, 64), 256, 0, stream>>>(
        x, memb, 384, ln1g, ln1b, Wqkv_c, bqkv_c, bufQKV, 1152, Vt, 768, nullptr, nullptr, nullptr);
    attn_mfma<<<dim3(16, 8, SPL), 256, 0, stream>>>(bufQKV, 1152, bufQKV + 384, 1152, Vt, Po, Pl);
    gemm_comb<<<dim3(6, 128), 256, 0, stream>>>(Po, Pl, nullptr, Wco, cbo, x, X1);

    // --- motif-gated self-attention: LN2 fused into QKV projection ---
    gemm_ln<0, true, true, false><<<dim3(18, 64), 256, 0, stream>>>(
        X1, nullptr, 1 << 30, ln2g, ln2b, Wqkv_s, bqkv_s, bufQKV, 1152, Vt, 768, nullptr, nullptr, nullptr);
    attn_mfma<<<dim3(16, 8, SPL), 256, 0, stream>>>(bufQKV, 1152, bufQKV + 384, 1152, Vt, Po, Pl);
    gemm_comb<<<dim3(6, 128), 256, 0, stream>>>(Po, Pl, gbuf, Wso, sbo, X1, X2);

    // --- FFN + LoRA: LN3 fused into f1 (adA as 25th block-col); LoRA-B fused into f2 ---
    gemm_ln<1, true, false, true><<<dim3(25, 64), 256, 0, stream>>>(
        X2, nullptr, 1 << 30, ln3g, ln3b, Wf1, f1b, F, 1536, nullptr, 0, WadA, Tl, aidx);
    gemm_f2<<<dim3(6, 128), 256, 0, stream>>>(
        F, Wf2, f2b, X2, (float*)d_out, 384, 1536, Tl, WadB, aidx);
}

// Round 13
// 365.069 us; speedup vs baseline: 1.0772x; 1.0772x over previous
//
#include <hip/hip_runtime.h>
#include <hip/hip_bf16.h>
#include <math.h>

// Problem constants
#define B_   2
#define T_   2048
#define M_   2048
#define D_   384
#define H_   4
#define DH_  96
#define NM_  8
#define DF_  1536
#define R_   16
#define NR_  4096   // B*T = B*M rows
#define SPL  8      // attention key-splits

typedef unsigned short u16;
typedef u16    u16x8  __attribute__((ext_vector_type(8)));
typedef u16    u16x4  __attribute__((ext_vector_type(4)));
typedef __bf16 bf16x8 __attribute__((ext_vector_type(8)));
typedef float  f32x4  __attribute__((ext_vector_type(4)));

union V8 { u16x8 u; bf16x8 b; };
__device__ __forceinline__ bf16x8 as_bf(u16x8 x) { V8 v; v.u = x; return v.b; }

__device__ __forceinline__ u16 f2bf(float f) {
    unsigned u = __float_as_uint(f);
    unsigned r = (u + 0x7fffu + ((u >> 16) & 1u)) >> 16;
    return (u16)r;
}
__device__ __forceinline__ float bf2f(u16 u) {
    return __uint_as_float(((unsigned)u) << 16);
}

// async global->LDS: 16B per lane, dest = wave-uniform base + lane*16
__device__ __forceinline__ void load16(const u16* g, u16* l) {
    __builtin_amdgcn_global_load_lds(
        (const __attribute__((address_space(1))) void*)g,
        (__attribute__((address_space(3))) void*)l, 16, 0, 0);
}

// ---------------- fused setup: weight converts + bias pack + gates ----------------
__global__ __launch_bounds__(256)
void setup_kernel(const float* cWq, const float* cWk, const float* cWv, const float* cWo,
                  const float* sWq, const float* sWk, const float* sWv, const float* sWo,
                  const float* f1W, const float* f2W, const float* adA, const float* adB,
                  const float* mem,
                  u16* Wqkv_c, u16* Wco, u16* Wqkv_s, u16* Wso,
                  u16* Wf1, u16* Wf2, u16* WadA, u16* WadB, u16* memb,
                  const float* cbq, const float* cbk, const float* cbv,
                  const float* sbq, const float* sbk, const float* sbv,
                  float* bqkv_c, float* bqkv_s,
                  const float* mc, const float* gW, const float* gb, float* gates) {
    int seg = blockIdx.y;
    if (seg == 13) {
        for (int i = blockIdx.x * 256 + threadIdx.x; i < 2312; i += gridDim.x * 256) {
            if (i < 1152) {
                bqkv_c[i] = (i < 384) ? cbq[i] : (i < 768 ? cbk[i - 384] : cbv[i - 768]);
            } else if (i < 2304) {
                int j = i - 1152;
                bqkv_s[j] = (j < 384) ? sbq[j] : (j < 768 ? sbk[j - 384] : sbv[j - 768]);
            } else {
                int k = i - 2304;  // 0..7
                int b = k / H_, h = k % H_;
                float s = gb[h];
                for (int n = 0; n < NM_; n++)
                    s += mc[b * NM_ + n] * gW[h * NM_ + n];
                gates[k] = 1.f / (1.f + __expf(-s));
            }
        }
        return;
    }
    const float* s; u16* d; int n;
    switch (seg) {
        case 0:  s = cWq; d = Wqkv_c;           n = 147456; break;
        case 1:  s = cWk; d = Wqkv_c + 147456;  n = 147456; break;
        case 2:  s = cWv; d = Wqkv_c + 294912;  n = 147456; break;
        case 3:  s = cWo; d = Wco;              n = 147456; break;
        case 4:  s = sWq; d = Wqkv_s;           n = 147456; break;
        case 5:  s = sWk; d = Wqkv_s + 147456;  n = 147456; break;
        case 6:  s = sWv; d = Wqkv_s + 294912;  n = 147456; break;
        case 7:  s = sWo; d = Wso;              n = 147456; break;
        case 8:  s = f1W; d = Wf1;              n = 589824; break;
        case 9:  s = f2W; d = Wf2;              n = 589824; break;
        case 10: s = adA; d = WadA;             n = 24576;  break;
        case 11: s = adB; d = WadB;             n = 24576;  break;
        default: s = mem; d = memb;             n = 1572864; break;
    }
    for (int i = blockIdx.x * 256 + threadIdx.x; i < n; i += gridDim.x * 256)
        d[i] = f2bf(s[i]);
}

// ---------------- LayerNorm: fp32 in, bf16 out ----------------
__global__ __launch_bounds__(384)
void ln_kernel(const float* __restrict__ x, const float* __restrict__ g,
               const float* __restrict__ b, u16* __restrict__ out) {
    __shared__ float sm[8];
    int row = blockIdx.x;
    int t = threadIdx.x;
    float v = x[(long)row * D_ + t];

    float s = v;
    for (int o = 32; o > 0; o >>= 1) s += __shfl_down(s, o);
    if ((t & 63) == 0) sm[t >> 6] = s;
    __syncthreads();
    float mu = 0.f;
    for (int i = 0; i < 6; i++) mu += sm[i];
    mu *= (1.f / D_);
    __syncthreads();

    float d = v - mu;
    s = d * d;
    for (int o = 32; o > 0; o >>= 1) s += __shfl_down(s, o);
    if ((t & 63) == 0) sm[t >> 6] = s;
    __syncthreads();
    float var = 0.f;
    for (int i = 0; i < 6; i++) var += sm[i];
    var *= (1.f / D_);

    float r = rsqrtf(var + 1e-5f);
    out[(long)row * D_ + t] = f2bf(d * r * g[t] + b[t]);
}

// ---------------- unified pipelined MFMA GEMM (R9-proven) ----------------
template<int MT, int ACT, bool OBF, bool VT, bool LORA, bool LORAA>
__global__ __launch_bounds__(256)
void gemm_uni(const u16* __restrict__ A0, const u16* __restrict__ A1, int aswitch,
              const u16* __restrict__ W, const float* __restrict__ bias,
              const float* __restrict__ res, void* __restrict__ Cout, int NC, int K,
              u16* __restrict__ Vt, int vtbase,
              const u16* __restrict__ Tl, const u16* __restrict__ adW,
              u16* __restrict__ TlOut, const int* __restrict__ aidx) {
    constexpr int NREG = 4 * MT + 8;
    constexpr int HALF = NREG * 512;
    __shared__ __align__(16) u16 S[2 * HALF];
    int tid = threadIdx.x, w = tid >> 6, lane = tid & 63;
    int l15 = lane & 15, quad = lane >> 4;
    int bm = blockIdx.y * (MT * 32), bn = blockIdx.x * 64;
    bool loraBlk = LORAA && (bn >= NC);

    const u16* Ap = (bn < aswitch) ? A0 : A1;
    const u16* Wb = W;
    if (LORAA && loraBlk) Wb = adW + (long)aidx[0] * 6144;

    const u16* GP[MT + 2];
    int LO[MT + 2];
    #pragma unroll
    for (int i = 0; i < MT + 2; i++) {
        int r = i * 4 + w;
        const u16* src;
        if (r < 4 * MT) {
            int mt = r >> 1, kc = r & 1;
            src = Ap + (long)(bm + mt * 16 + l15) * K + kc * 32 + quad * 8;
        } else {
            int rw = r - 4 * MT, nt = rw >> 1, kc = rw & 1;
            if (LORAA && loraBlk)
                src = Wb + (long)((nt * 16 + l15) & 15) * K + kc * 32 + quad * 8;
            else
                src = Wb + (long)(bn + nt * 16 + l15) * K + kc * 32 + quad * 8;
        }
        GP[i] = src;
        LO[i] = r * 512;
    }

    f32x4 acc[MT][2];
    #pragma unroll
    for (int s = 0; s < MT; s++)
        #pragma unroll
        for (int j = 0; j < 2; j++) acc[s][j] = (f32x4){0.f, 0.f, 0.f, 0.f};

    int niter = K >> 6;
    #pragma unroll
    for (int i = 0; i < MT + 2; i++) load16(GP[i], S + LO[i]);

    for (int it = 0; it < niter; it++) {
        __syncthreads();
        int cur = (it & 1) * HALF, nxt = HALF - cur;
        if (it + 1 < niter) {
            int k = (it + 1) << 6;
            #pragma unroll
            for (int i = 0; i < MT + 2; i++) load16(GP[i] + k, S + nxt + LO[i]);
        }
        #pragma unroll
        for (int kc = 0; kc < 2; kc++) {
            u16x8 af[MT], bfv[2];
            #pragma unroll
            for (int s = 0; s < MT; s++)
                af[s] = *(const u16x8*)(S + cur + (((w & 1) * MT + s) * 2 + kc) * 512 + lane * 8);
            #pragma unroll
            for (int j = 0; j < 2; j++)
                bfv[j] = *(const u16x8*)(S + cur + (4 * MT + (((w >> 1) * 2 + j) * 2 + kc)) * 512 + lane * 8);
            #pragma unroll
            for (int s = 0; s < MT; s++)
                #pragma unroll
                for (int j = 0; j < 2; j++)
                    acc[s][j] = __builtin_amdgcn_mfma_f32_16x16x32_bf16(
                        as_bf(af[s]), as_bf(bfv[j]), acc[s][j], 0, 0, 0);
        }
    }

    if (LORA) {
        long ao = (long)aidx[0] * 6144;
        u16x8 tlf[MT], adf[2];
        #pragma unroll
        for (int s = 0; s < MT; s++) {
            #pragma unroll
            for (int e = 0; e < 8; e++) tlf[s][e] = 0;
            if (quad < 2)
                tlf[s] = *(const u16x8*)(Tl + (long)(bm + ((w & 1) * MT + s) * 16 + l15) * 16 + quad * 8);
        }
        #pragma unroll
        for (int j = 0; j < 2; j++) {
            #pragma unroll
            for (int e = 0; e < 8; e++) adf[j][e] = 0;
            if (quad < 2)
                adf[j] = *(const u16x8*)(adW + ao + (long)(bn + ((w >> 1) * 2 + j) * 16 + l15) * 16 + quad * 8);
        }
        #pragma unroll
        for (int s = 0; s < MT; s++)
            #pragma unroll
            for (int j = 0; j < 2; j++)
                acc[s][j] = __builtin_amdgcn_mfma_f32_16x16x32_bf16(
                    as_bf(tlf[s]), as_bf(adf[j]), acc[s][j], 0, 0, 0);
    }

    #pragma unroll
    for (int mi = 0; mi < MT; mi++) {
        int mt = (w & 1) * MT + mi;
        int rowb = bm + mt * 16 + quad * 4;
        #pragma unroll
        for (int nj = 0; nj < 2; nj++) {
            int coll = ((w >> 1) * 2 + nj) * 16 + l15;
            int col = bn + coll;
            if (LORAA && loraBlk) {
                if (coll < 16) {
                    #pragma unroll
                    for (int r = 0; r < 4; r++)
                        TlOut[(long)(rowb + r) * 16 + coll] = f2bf(acc[mi][nj][r]);
                }
            } else {
                float bv = bias ? bias[col] : 0.f;
                if (VT && col >= vtbase) {
                    int vc = col - vtbase;
                    int b = rowb >> 11, rowl = rowb & 2047;
                    u16x4 ov;
                    #pragma unroll
                    for (int r = 0; r < 4; r++) ov[r] = f2bf(acc[mi][nj][r] + bv);
                    *(u16x4*)(Vt + ((long)b * 384 + vc) * 2048 + rowl) = ov;
                } else {
                    #pragma unroll
                    for (int r = 0; r < 4; r++) {
                        float v = acc[mi][nj][r] + bv;
                        if (ACT == 1) v = 0.5f * v * (1.f + erff(v * 0.70710678118654752f));
                        long idx = (long)(rowb + r) * NC + col;
                        if (res) v += res[idx];
                        if (OBF) ((u16*)Cout)[idx] = f2bf(v);
                        else     ((float*)Cout)[idx] = v;
                    }
                }
            }
        }
    }
}

// ---------------- Flash attention: 64 Q-rows/wave (4 subtiles), 32-key chunks, K/V dbuf ----------------
// grid (8, 8, 8): 256 Q-rows per block, one (b,h) per y, 256 keys per z-split, 8 iters of 32 keys.
// Per iter per wave: 6 K + 6 V + 4 P ds_read_b128 feed 48 MFMA (0.33 reads/MFMA vs R9's 0.58).
// LDS 40 KB; one barrier per iter (prefetch DMA issued right after).
__global__ __launch_bounds__(256)
void attn_mfma(const u16* __restrict__ Qg, int qs,
               const u16* __restrict__ Kg, int ks,
               const u16* __restrict__ Vt,
               u16* __restrict__ Po, float* __restrict__ Pl) {
    __shared__ __align__(16) u16 Ks[2][3072];   // 6 regions of 512: region = ksub*3+kstep
    __shared__ __align__(16) u16 Vs[2][3072];   // 6 regions of 512: region = nt
    __shared__ __align__(16) u16 Ps[4][4][512]; // per (wave, subtile), A-frag order stride-128
    const float SCALE = 0.10206207261596575f;   // 1/sqrt(96)

    int tid = threadIdx.x, wv = tid >> 6, lane = tid & 63;
    int l15 = lane & 15, quad = lane >> 4;
    int bh = blockIdx.y, b = bh >> 2, h = bh & 3;
    int split = blockIdx.z;
    int q0 = blockIdx.x * 256 + wv * 64;

    const u16* Qb = Qg + (long)(b * 2048 + q0) * qs + h * 96;
    const u16* Kb = Kg + (long)(b * 2048 + split * 256) * ks + h * 96;
    const u16* Vb = Vt + (long)(b * 384 + h * 96) * 2048 + split * 256;

    u16x8 qf[4][3];
    #pragma unroll
    for (int g = 0; g < 4; g++)
        #pragma unroll
        for (int t = 0; t < 3; t++)
            qf[g][t] = *(const u16x8*)(Qb + (long)(g * 16 + l15) * qs + t * 32 + quad * 8);

    f32x4 o[4][6];
    #pragma unroll
    for (int g = 0; g < 4; g++)
        #pragma unroll
        for (int i = 0; i < 6; i++) o[g][i] = (f32x4){0.f, 0.f, 0.f, 0.f};
    float rs[4][4];
    #pragma unroll
    for (int g = 0; g < 4; g++)
        #pragma unroll
        for (int r = 0; r < 4; r++) rs[g][r] = 0.f;

    // staging: 12 regions (6 K + 6 V), 3 issues per wave, per-iter source stride in ST
    const u16* GI[3]; u16* LB[3]; long ST[3];
    #pragma unroll
    for (int i = 0; i < 3; i++) {
        int r = i * 4 + wv;
        if (r < 6) {
            int ksub = r / 3, kst = r - ksub * 3;
            GI[i] = Kb + (long)(ksub * 16 + l15) * ks + kst * 32 + quad * 8;
            LB[i] = &Ks[0][0] + r * 512;
            ST[i] = (long)32 * ks;
        } else {
            int nt = r - 6;
            GI[i] = Vb + (long)(nt * 16 + l15) * 2048 + quad * 8;
            LB[i] = &Vs[0][0] + nt * 512;
            ST[i] = 32;
        }
    }

    // prologue: prefetch iter 0 into buffer 0
    #pragma unroll
    for (int i = 0; i < 3; i++) load16(GI[i], LB[i]);

    for (int it = 0; it < 8; it++) {
        __syncthreads();   // drains DMA for buf[it&1]; all waves past reads of buf[nxt]
        int cur = it & 1, nxt = cur ^ 1;
        if (it + 1 < 8) {
            #pragma unroll
            for (int i = 0; i < 3; i++)
                load16(GI[i] + (long)(it + 1) * ST[i], LB[i] + nxt * 3072);
        }

        // scores: 2 key-subtiles x 3 k-steps; each kf feeds 4 Q-subtiles
        f32x4 sc[4][2];
        #pragma unroll
        for (int g = 0; g < 4; g++)
            #pragma unroll
            for (int s = 0; s < 2; s++) sc[g][s] = (f32x4){0.f, 0.f, 0.f, 0.f};
        #pragma unroll
        for (int s = 0; s < 2; s++)
            #pragma unroll
            for (int t = 0; t < 3; t++) {
                u16x8 kf = *(const u16x8*)(&Ks[cur][0] + (s * 3 + t) * 512 + lane * 8);
                #pragma unroll
                for (int g = 0; g < 4; g++)
                    sc[g][s] = __builtin_amdgcn_mfma_f32_16x16x32_bf16(
                        as_bf(qf[g][t]), as_bf(kf), sc[g][s], 0, 0, 0);
            }

        // p = exp(s*scale); accumulate sums; write P (C-layout -> A-frag LDS, stride 128)
        #pragma unroll
        for (int g = 0; g < 4; g++)
            #pragma unroll
            for (int s = 0; s < 2; s++) {
                int base = (((s << 1) | (l15 >> 3))) * 128 + (l15 & 7);
                #pragma unroll
                for (int r = 0; r < 4; r++) {
                    float p = __expf(sc[g][s][r] * SCALE);
                    rs[g][r] += p;
                    Ps[wv][g][base + (quad * 4 + r) * 8] = f2bf(p);
                }
            }

        // PV: each vf feeds 4 Q-subtiles
        u16x8 pf[4];
        #pragma unroll
        for (int g = 0; g < 4; g++)
            pf[g] = *(const u16x8*)(&Ps[wv][g][0] + quad * 128 + l15 * 8);
        #pragma unroll
        for (int nt = 0; nt < 6; nt++) {
            u16x8 vf = *(const u16x8*)(&Vs[cur][0] + nt * 512 + lane * 8);
            #pragma unroll
            for (int g = 0; g < 4; g++)
                o[g][nt] = __builtin_amdgcn_mfma_f32_16x16x32_bf16(
                    as_bf(pf[g]), as_bf(vf), o[g][nt], 0, 0, 0);
        }
    }

    #pragma unroll
    for (int off = 1; off < 16; off <<= 1)
        #pragma unroll
        for (int g = 0; g < 4; g++)
            #pragma unroll
            for (int r = 0; r < 4; r++) rs[g][r] += __shfl_xor(rs[g][r], off);

    #pragma unroll
    for (int g = 0; g < 4; g++) {
        u16* Pob = Po + ((long)(split * 8 + bh) * 2048 + q0 + g * 16) * 96;
        #pragma unroll
        for (int nt = 0; nt < 6; nt++)
            #pragma unroll
            for (int r = 0; r < 4; r++)
                Pob[(long)(quad * 4 + r) * 96 + nt * 16 + l15] = f2bf(o[g][nt][r]);
        if (l15 == 0) {
            long mb = (long)(split * 8 + bh) * 2048 + q0 + g * 16 + quad * 4;
            #pragma unroll
            for (int r = 0; r < 4; r++) Pl[mb + r] = rs[g][r];
        }
    }
}

// ---------------- combine SPL key-split partials (bf16) -> Z (bf16, gate/l applied) ----------------
__global__ __launch_bounds__(256)
void attn_combine(const u16* __restrict__ Po, const float* __restrict__ Pl,
                  const float* __restrict__ gates, u16* __restrict__ Z) {
    int bh = blockIdx.y, b = bh >> 2, h = bh & 3;
    int tid = threadIdx.x;
    int rl = tid >> 2, part = tid & 3;
    int row = blockIdx.x * 64 + rl;
    long rbase = (long)bh * 2048 + row;

    float L = 0.f;
    #pragma unroll
    for (int s = 0; s < SPL; s++) L += Pl[s * 16384 + rbase];
    float g = gates ? gates[bh] : 1.f;
    float sc = g / L;

    u16* Zr = Z + ((long)(b * 2048) + row) * 384 + h * 96 + part * 24;
    #pragma unroll
    for (int i = 0; i < 24; i += 4) {
        f32x4 acc = (f32x4){0.f, 0.f, 0.f, 0.f};
        #pragma unroll
        for (int s = 0; s < SPL; s++) {
            u16x4 v = *(const u16x4*)(Po + ((long)s * 16384 + rbase) * 96 + part * 24 + i);
            #pragma unroll
            for (int e = 0; e < 4; e++) acc[e] += bf2f(v[e]);
        }
        u16x4 ov;
        #pragma unroll
        for (int e = 0; e < 4; e++) ov[e] = f2bf(acc[e] * sc);
        *(u16x4*)(Zr + i) = ov;
    }
}

// ---------------- Launch ----------------
extern "C" void kernel_launch(void* const* d_in, const int* in_sizes, int n_in,
                              void* d_out, int out_size, void* d_ws, size_t ws_size,
                              hipStream_t stream) {
    const float* x    = (const float*)d_in[0];
    const float* mem  = (const float*)d_in[1];
    const float* mc   = (const float*)d_in[2];
    const int*   aidx = (const int*)d_in[3];
    const float* cWq = (const float*)d_in[4],  *cbq = (const float*)d_in[5];
    const float* cWk = (const float*)d_in[6],  *cbk = (const float*)d_in[7];
    const float* cWv = (const float*)d_in[8],  *cbv = (const float*)d_in[9];
    const float* cWo = (const float*)d_in[10], *cbo = (const float*)d_in[11];
    const float* sWq = (const float*)d_in[12], *sbq = (const float*)d_in[13];
    const float* sWk = (const float*)d_in[14], *sbk = (const float*)d_in[15];
    const float* sWv = (const float*)d_in[16], *sbv = (const float*)d_in[17];
    const float* sWo = (const float*)d_in[18], *sbo = (const float*)d_in[19];
    const float* gW  = (const float*)d_in[20], *gb  = (const float*)d_in[21];
    const float* f1W = (const float*)d_in[22], *f1b = (const float*)d_in[23];
    const float* f2W = (const float*)d_in[24], *f2b = (const float*)d_in[25];
    const float* adA = (const float*)d_in[26], *adB = (const float*)d_in[27];
    const float* ln1g = (const float*)d_in[28], *ln1b = (const float*)d_in[29];
    const float* ln2g = (const float*)d_in[30], *ln2b = (const float*)d_in[31];
    const float* ln3g = (const float*)d_in[32], *ln3b = (const float*)d_in[33];

    // ---- workspace layout ----
    u16* p = (u16*)d_ws;
    u16* H      = p; p += (size_t)NR_ * 384;
    u16* bufQKV = p; p += (size_t)NR_ * 1152;
    u16* Vt     = p; p += (size_t)B_ * 384 * 2048;
    u16* Zb     = p; p += (size_t)NR_ * 384;
    u16* F      = p; p += (size_t)NR_ * 1536;
    u16* Tl     = p; p += (size_t)NR_ * 16;
    u16* memb   = p; p += (size_t)NR_ * 384;
    u16* Wqkv_c = p; p += 442368;
    u16* Wco    = p; p += 147456;
    u16* Wqkv_s = p; p += 442368;
    u16* Wso    = p; p += 147456;
    u16* Wf1    = p; p += 589824;
    u16* Wf2    = p; p += 589824;
    u16* WadA   = p; p += 24576;
    u16* WadB   = p; p += 24576;
    u16* Po     = p; p += (size_t)SPL * 8 * 2048 * 96;
    float* fp = (float*)(((size_t)p + 3) & ~(size_t)3);
    float* X1 = fp;     fp += (size_t)NR_ * 384;
    float* X2 = fp;     fp += (size_t)NR_ * 384;
    float* Pl = fp;     fp += (size_t)SPL * 8 * 2048;
    float* bqkv_c = fp; fp += 1152;
    float* bqkv_s = fp; fp += 1152;
    float* gbuf   = fp; fp += 8;

    // ---- fused setup ----
    setup_kernel<<<dim3(96, 14), 256, 0, stream>>>(
        cWq, cWk, cWv, cWo, sWq, sWk, sWv, sWo, f1W, f2W, adA, adB, mem,
        Wqkv_c, Wco, Wqkv_s, Wso, Wf1, Wf2, WadA, WadB, memb,
        cbq, cbk, cbv, sbq, sbk, sbv, bqkv_c, bqkv_s, mc, gW, gb, gbuf);

    const float* nf = nullptr;
    const u16* nu = nullptr;
    // --- cross-attention: merged QKV projection (Q from H, K/V from memb) ---
    ln_kernel<<<NR_, 384, 0, stream>>>(x, ln1g, ln1b, H);
    gemm_uni<2, 0, true, true, false, false><<<dim3(18, 64), 256, 0, stream>>>(
        H, memb, 384, Wqkv_c, bqkv_c, nf, bufQKV, 1152, 384, Vt, 768, nu, nu, nullptr, nullptr);
    attn_mfma<<<dim3(8, 8, SPL), 256, 0, stream>>>(bufQKV, 1152, bufQKV + 384, 1152, Vt, Po, Pl);
    attn_combine<<<dim3(32, 8), 256, 0, stream>>>(Po, Pl, nullptr, Zb);
    gemm_uni<1, 0, false, false, false, false><<<dim3(6, 128), 256, 0, stream>>>(
        Zb, Zb, 0, Wco, cbo, x, X1, 384, 384, nullptr, 0, nu, nu, nullptr, nullptr);

    // --- motif-gated self-attention ---
    ln_kernel<<<NR_, 384, 0, stream>>>(X1, ln2g, ln2b, H);
    gemm_uni<2, 0, true, true, false, false><<<dim3(18, 64), 256, 0, stream>>>(
        H, H, 0, Wqkv_s, bqkv_s, nf, bufQKV, 1152, 384, Vt, 768, nu, nu, nullptr, nullptr);
    attn_mfma<<<dim3(8, 8, SPL), 256, 0, stream>>>(bufQKV, 1152, bufQKV + 384, 1152, Vt, Po, Pl);
    attn_combine<<<dim3(32, 8), 256, 0, stream>>>(Po, Pl, gbuf, Zb);
    gemm_uni<1, 0, false, false, false, false><<<dim3(6, 128), 256, 0, stream>>>(
        Zb, Zb, 0, Wso, sbo, X1, X2, 384, 384, nullptr, 0, nu, nu, nullptr, nullptr);

    // --- FFN + LoRA (adA fused into f1 as 25th block-col; loraB fused into f2 epilogue) ---
    ln_kernel<<<NR_, 384, 0, stream>>>(X2, ln3g, ln3b, H);
    gemm_uni<2, 1, true, false, false, true><<<dim3(25, 64), 256, 0, stream>>>(
        H, H, 0, Wf1, f1b, nf, F, 1536, 384, nullptr, 0, nu, WadA, Tl, aidx);
    gemm_uni<1, 0, false, false, true, false><<<dim3(6, 128), 256, 0, stream>>>(
        F, F, 0, Wf2, f2b, X2, d_out, 384, 1536, nullptr, 0, Tl, WadB, nullptr, aidx);
}

// Round 14
// 350.118 us; speedup vs baseline: 1.1232x; 1.0427x over previous
//
#include <hip/hip_runtime.h>
#include <hip/hip_bf16.h>
#include <math.h>

// Problem constants
#define B_   2
#define T_   2048
#define M_   2048
#define D_   384
#define H_   4
#define DH_  96
#define NM_  8
#define DF_  1536
#define R_   16
#define NR_  4096   // B*T = B*M rows
#define SPL  4      // attention key-splits

typedef unsigned short u16;
typedef u16    u16x8  __attribute__((ext_vector_type(8)));
typedef u16    u16x4  __attribute__((ext_vector_type(4)));
typedef __bf16 bf16x8 __attribute__((ext_vector_type(8)));
typedef float  f32x4  __attribute__((ext_vector_type(4)));

union V8 { u16x8 u; bf16x8 b; };
__device__ __forceinline__ bf16x8 as_bf(u16x8 x) { V8 v; v.u = x; return v.b; }

__device__ __forceinline__ u16 f2bf(float f) {
    unsigned u = __float_as_uint(f);
    unsigned r = (u + 0x7fffu + ((u >> 16) & 1u)) >> 16;
    return (u16)r;
}
__device__ __forceinline__ float bf2f(u16 u) {
    return __uint_as_float(((unsigned)u) << 16);
}

// async global->LDS: 16B per lane, dest = wave-uniform base + lane*16
__device__ __forceinline__ void load16(const u16* g, u16* l) {
    __builtin_amdgcn_global_load_lds(
        (const __attribute__((address_space(1))) void*)g,
        (__attribute__((address_space(3))) void*)l, 16, 0, 0);
}

// ---------------- fused setup: weight converts + bias pack + gates ----------------
__global__ __launch_bounds__(256)
void setup_kernel(const float* cWq, const float* cWk, const float* cWv, const float* cWo,
                  const float* sWq, const float* sWk, const float* sWv, const float* sWo,
                  const float* f1W, const float* f2W, const float* adA, const float* adB,
                  const float* mem,
                  u16* Wqkv_c, u16* Wco, u16* Wqkv_s, u16* Wso,
                  u16* Wf1, u16* Wf2, u16* WadA, u16* WadB, u16* memb,
                  const float* cbq, const float* cbk, const float* cbv,
                  const float* sbq, const float* sbk, const float* sbv,
                  float* bqkv_c, float* bqkv_s,
                  const float* mc, const float* gW, const float* gb, float* gates) {
    int seg = blockIdx.y;
    if (seg == 13) {
        for (int i = blockIdx.x * 256 + threadIdx.x; i < 2312; i += gridDim.x * 256) {
            if (i < 1152) {
                bqkv_c[i] = (i < 384) ? cbq[i] : (i < 768 ? cbk[i - 384] : cbv[i - 768]);
            } else if (i < 2304) {
                int j = i - 1152;
                bqkv_s[j] = (j < 384) ? sbq[j] : (j < 768 ? sbk[j - 384] : sbv[j - 768]);
            } else {
                int k = i - 2304;  // 0..7
                int b = k / H_, h = k % H_;
                float s = gb[h];
                for (int n = 0; n < NM_; n++)
                    s += mc[b * NM_ + n] * gW[h * NM_ + n];
                gates[k] = 1.f / (1.f + __expf(-s));
            }
        }
        return;
    }
    const float* s; u16* d; int n;
    switch (seg) {
        case 0:  s = cWq; d = Wqkv_c;           n = 147456; break;
        case 1:  s = cWk; d = Wqkv_c + 147456;  n = 147456; break;
        case 2:  s = cWv; d = Wqkv_c + 294912;  n = 147456; break;
        case 3:  s = cWo; d = Wco;              n = 147456; break;
        case 4:  s = sWq; d = Wqkv_s;           n = 147456; break;
        case 5:  s = sWk; d = Wqkv_s + 147456;  n = 147456; break;
        case 6:  s = sWv; d = Wqkv_s + 294912;  n = 147456; break;
        case 7:  s = sWo; d = Wso;              n = 147456; break;
        case 8:  s = f1W; d = Wf1;              n = 589824; break;
        case 9:  s = f2W; d = Wf2;              n = 589824; break;
        case 10: s = adA; d = WadA;             n = 24576;  break;
        case 11: s = adB; d = WadB;             n = 24576;  break;
        default: s = mem; d = memb;             n = 1572864; break;
    }
    for (int i = blockIdx.x * 256 + threadIdx.x; i < n; i += gridDim.x * 256)
        d[i] = f2bf(s[i]);
}

// ---------------- LayerNorm: fp32 in, bf16 out ----------------
__global__ __launch_bounds__(384)
void ln_kernel(const float* __restrict__ x, const float* __restrict__ g,
               const float* __restrict__ b, u16* __restrict__ out) {
    __shared__ float sm[8];
    int row = blockIdx.x;
    int t = threadIdx.x;
    float v = x[(long)row * D_ + t];

    float s = v;
    for (int o = 32; o > 0; o >>= 1) s += __shfl_down(s, o);
    if ((t & 63) == 0) sm[t >> 6] = s;
    __syncthreads();
    float mu = 0.f;
    for (int i = 0; i < 6; i++) mu += sm[i];
    mu *= (1.f / D_);
    __syncthreads();

    float d = v - mu;
    s = d * d;
    for (int o = 32; o > 0; o >>= 1) s += __shfl_down(s, o);
    if ((t & 63) == 0) sm[t >> 6] = s;
    __syncthreads();
    float var = 0.f;
    for (int i = 0; i < 6; i++) var += sm[i];
    var *= (1.f / D_);

    float r = rsqrtf(var + 1e-5f);
    out[(long)row * D_ + t] = f2bf(d * r * g[t] + b[t]);
}

// ---------------- unified pipelined MFMA GEMM ----------------
// MT: m-tiles per wave (2 -> 64-row block; 1 -> 32-row block). BK=64, dbuf, 1 barrier/iter.
// A-switch: blocks with bn < aswitch read A0, else A1.
// VT: cols >= vtbase written transposed to Vt[B][384][2048].
// LORA: += Tl @ adW[aidx]^T via extra MFMA. LORAA: block col NC/64 computes Tl = A @ adW[aidx]^T.
template<int MT, int ACT, bool OBF, bool VT, bool LORA, bool LORAA>
__global__ __launch_bounds__(256)
void gemm_uni(const u16* __restrict__ A0, const u16* __restrict__ A1, int aswitch,
              const u16* __restrict__ W, const float* __restrict__ bias,
              const float* __restrict__ res, void* __restrict__ Cout, int NC, int K,
              u16* __restrict__ Vt, int vtbase,
              const u16* __restrict__ Tl, const u16* __restrict__ adW,
              u16* __restrict__ TlOut, const int* __restrict__ aidx) {
    constexpr int NREG = 4 * MT + 8;
    constexpr int HALF = NREG * 512;
    __shared__ __align__(16) u16 S[2 * HALF];
    int tid = threadIdx.x, w = tid >> 6, lane = tid & 63;
    int l15 = lane & 15, quad = lane >> 4;
    int bm = blockIdx.y * (MT * 32), bn = blockIdx.x * 64;
    bool loraBlk = LORAA && (bn >= NC);

    const u16* Ap = (bn < aswitch) ? A0 : A1;
    const u16* Wb = W;
    if (LORAA && loraBlk) Wb = adW + (long)aidx[0] * 6144;

    const u16* GP[MT + 2];
    int LO[MT + 2];
    #pragma unroll
    for (int i = 0; i < MT + 2; i++) {
        int r = i * 4 + w;
        const u16* src;
        if (r < 4 * MT) {
            int mt = r >> 1, kc = r & 1;
            src = Ap + (long)(bm + mt * 16 + l15) * K + kc * 32 + quad * 8;
        } else {
            int rw = r - 4 * MT, nt = rw >> 1, kc = rw & 1;
            if (LORAA && loraBlk)
                src = Wb + (long)((nt * 16 + l15) & 15) * K + kc * 32 + quad * 8;
            else
                src = Wb + (long)(bn + nt * 16 + l15) * K + kc * 32 + quad * 8;
        }
        GP[i] = src;
        LO[i] = r * 512;
    }

    f32x4 acc[MT][2];
    #pragma unroll
    for (int s = 0; s < MT; s++)
        #pragma unroll
        for (int j = 0; j < 2; j++) acc[s][j] = (f32x4){0.f, 0.f, 0.f, 0.f};

    int niter = K >> 6;
    #pragma unroll
    for (int i = 0; i < MT + 2; i++) load16(GP[i], S + LO[i]);

    for (int it = 0; it < niter; it++) {
        __syncthreads();
        int cur = (it & 1) * HALF, nxt = HALF - cur;
        if (it + 1 < niter) {
            int k = (it + 1) << 6;
            #pragma unroll
            for (int i = 0; i < MT + 2; i++) load16(GP[i] + k, S + nxt + LO[i]);
        }
        #pragma unroll
        for (int kc = 0; kc < 2; kc++) {
            u16x8 af[MT], bfv[2];
            #pragma unroll
            for (int s = 0; s < MT; s++)
                af[s] = *(const u16x8*)(S + cur + (((w & 1) * MT + s) * 2 + kc) * 512 + lane * 8);
            #pragma unroll
            for (int j = 0; j < 2; j++)
                bfv[j] = *(const u16x8*)(S + cur + (4 * MT + (((w >> 1) * 2 + j) * 2 + kc)) * 512 + lane * 8);
            #pragma unroll
            for (int s = 0; s < MT; s++)
                #pragma unroll
                for (int j = 0; j < 2; j++)
                    acc[s][j] = __builtin_amdgcn_mfma_f32_16x16x32_bf16(
                        as_bf(af[s]), as_bf(bfv[j]), acc[s][j], 0, 0, 0);
        }
    }

    if (LORA) {
        long ao = (long)aidx[0] * 6144;
        u16x8 tlf[MT], adf[2];
        #pragma unroll
        for (int s = 0; s < MT; s++) {
            #pragma unroll
            for (int e = 0; e < 8; e++) tlf[s][e] = 0;
            if (quad < 2)
                tlf[s] = *(const u16x8*)(Tl + (long)(bm + ((w & 1) * MT + s) * 16 + l15) * 16 + quad * 8);
        }
        #pragma unroll
        for (int j = 0; j < 2; j++) {
            #pragma unroll
            for (int e = 0; e < 8; e++) adf[j][e] = 0;
            if (quad < 2)
                adf[j] = *(const u16x8*)(adW + ao + (long)(bn + ((w >> 1) * 2 + j) * 16 + l15) * 16 + quad * 8);
        }
        #pragma unroll
        for (int s = 0; s < MT; s++)
            #pragma unroll
            for (int j = 0; j < 2; j++)
                acc[s][j] = __builtin_amdgcn_mfma_f32_16x16x32_bf16(
                    as_bf(tlf[s]), as_bf(adf[j]), acc[s][j], 0, 0, 0);
    }

    #pragma unroll
    for (int mi = 0; mi < MT; mi++) {
        int mt = (w & 1) * MT + mi;
        int rowb = bm + mt * 16 + quad * 4;
        #pragma unroll
        for (int nj = 0; nj < 2; nj++) {
            int coll = ((w >> 1) * 2 + nj) * 16 + l15;
            int col = bn + coll;
            if (LORAA && loraBlk) {
                if (coll < 16) {
                    #pragma unroll
                    for (int r = 0; r < 4; r++)
                        TlOut[(long)(rowb + r) * 16 + coll] = f2bf(acc[mi][nj][r]);
                }
            } else {
                float bv = bias ? bias[col] : 0.f;
                if (VT && col >= vtbase) {
                    int vc = col - vtbase;
                    int b = rowb >> 11, rowl = rowb & 2047;
                    u16x4 ov;
                    #pragma unroll
                    for (int r = 0; r < 4; r++) ov[r] = f2bf(acc[mi][nj][r] + bv);
                    *(u16x4*)(Vt + ((long)b * 384 + vc) * 2048 + rowl) = ov;
                } else {
                    #pragma unroll
                    for (int r = 0; r < 4; r++) {
                        float v = acc[mi][nj][r] + bv;
                        if (ACT == 1) v = 0.5f * v * (1.f + erff(v * 0.70710678118654752f));
                        long idx = (long)(rowb + r) * NC + col;
                        if (res) v += res[idx];
                        if (OBF) ((u16*)Cout)[idx] = f2bf(v);
                        else     ((float*)Cout)[idx] = v;
                    }
                }
            }
        }
    }
}

// ---------------- Flash attention: 32 Q-rows/wave (2 subtiles), dbuf K/V, key-split x4 ----------------
__global__ __launch_bounds__(256)
void attn_mfma(const u16* __restrict__ Qg, int qs,
               const u16* __restrict__ Kg, int ks,
               const u16* __restrict__ Vt,
               u16* __restrict__ Po, float* __restrict__ Pl) {
    __shared__ __align__(16) u16 Ks[2][6144];
    __shared__ __align__(16) u16 Vs[2][6144];
    __shared__ __align__(16) u16 Ps[4][2][1088];
    const float SCALE = 0.10206207261596575f;  // 1/sqrt(96)

    int tid = threadIdx.x, wv = tid >> 6, lane = tid & 63;
    int l15 = lane & 15, quad = lane >> 4;
    int bh = blockIdx.y, b = bh >> 2, h = bh & 3;
    int split = blockIdx.z;
    int q0 = blockIdx.x * 128 + wv * 32;

    const u16* Qb = Qg + (long)(b * 2048 + q0) * qs + h * 96;
    const u16* Kb = Kg + (long)(b * 2048 + split * 512) * ks + h * 96;
    const u16* Vb = Vt + (long)(b * 384 + h * 96) * 2048 + split * 512;

    u16x8 qf[2][3];
    #pragma unroll
    for (int g = 0; g < 2; g++)
        #pragma unroll
        for (int t = 0; t < 3; t++)
            qf[g][t] = *(const u16x8*)(Qb + (long)(g * 16 + l15) * qs + t * 32 + quad * 8);

    f32x4 o[2][6];
    #pragma unroll
    for (int g = 0; g < 2; g++)
        #pragma unroll
        for (int i = 0; i < 6; i++) o[g][i] = (f32x4){0.f, 0.f, 0.f, 0.f};
    float rs[2][4] = {{0.f, 0.f, 0.f, 0.f}, {0.f, 0.f, 0.f, 0.f}};

    const u16* KgI[3]; int KlO[3]; const u16* VgI[3]; int VlO[3];
    #pragma unroll
    for (int i = 0; i < 3; i++) {
        int r = i * 4 + wv;
        int ksub = r & 3, kst = r >> 2;
        KgI[i] = Kb + (long)(ksub * 16 + l15) * ks + kst * 32 + quad * 8;
        KlO[i] = (ksub * 3 + kst) * 512;
        int nt = r >> 1, t2 = r & 1;
        VgI[i] = Vb + (long)(nt * 16 + l15) * 2048 + t2 * 32 + quad * 8;
        VlO[i] = r * 512;
    }

    #pragma unroll
    for (int i = 0; i < 3; i++) {
        load16(KgI[i], &Ks[0][0] + KlO[i]);
        load16(VgI[i], &Vs[0][0] + VlO[i]);
    }

    for (int it = 0; it < 8; it++) {
        __syncthreads();
        int cur = it & 1, nxt = cur ^ 1;
        if (it + 1 < 8) {
            int j = (it + 1) * 64;
            #pragma unroll
            for (int i = 0; i < 3; i++) {
                load16(KgI[i] + (long)j * ks, &Ks[nxt][0] + KlO[i]);
                load16(VgI[i] + j, &Vs[nxt][0] + VlO[i]);
            }
        }

        f32x4 sc[2][4];
        #pragma unroll
        for (int g = 0; g < 2; g++)
            #pragma unroll
            for (int s = 0; s < 4; s++) sc[g][s] = (f32x4){0.f, 0.f, 0.f, 0.f};
        #pragma unroll
        for (int s = 0; s < 4; s++)
            #pragma unroll
            for (int t = 0; t < 3; t++) {
                u16x8 kf = *(const u16x8*)(&Ks[cur][0] + (s * 3 + t) * 512 + lane * 8);
                sc[0][s] = __builtin_amdgcn_mfma_f32_16x16x32_bf16(as_bf(qf[0][t]), as_bf(kf), sc[0][s], 0, 0, 0);
                sc[1][s] = __builtin_amdgcn_mfma_f32_16x16x32_bf16(as_bf(qf[1][t]), as_bf(kf), sc[1][s], 0, 0, 0);
            }

        #pragma unroll
        for (int g = 0; g < 2; g++)
            #pragma unroll
            for (int s = 0; s < 4; s++) {
                int base = (s >> 1) * 544 + ((((s & 1) << 1) | (l15 >> 3))) * 136 + (l15 & 7);
                #pragma unroll
                for (int r = 0; r < 4; r++) {
                    float p = __expf(sc[g][s][r] * SCALE);
                    rs[g][r] += p;
                    Ps[wv][g][base + (quad * 4 + r) * 8] = f2bf(p);
                }
            }

        #pragma unroll
        for (int t2 = 0; t2 < 2; t2++) {
            u16x8 pf0 = *(const u16x8*)(&Ps[wv][0][0] + t2 * 544 + quad * 136 + l15 * 8);
            u16x8 pf1 = *(const u16x8*)(&Ps[wv][1][0] + t2 * 544 + quad * 136 + l15 * 8);
            #pragma unroll
            for (int nt = 0; nt < 6; nt++) {
                u16x8 vf = *(const u16x8*)(&Vs[cur][0] + (nt * 2 + t2) * 512 + lane * 8);
                o[0][nt] = __builtin_amdgcn_mfma_f32_16x16x32_bf16(as_bf(pf0), as_bf(vf), o[0][nt], 0, 0, 0);
                o[1][nt] = __builtin_amdgcn_mfma_f32_16x16x32_bf16(as_bf(pf1), as_bf(vf), o[1][nt], 0, 0, 0);
            }
        }
    }

    #pragma unroll
    for (int off = 1; off < 16; off <<= 1)
        #pragma unroll
        for (int g = 0; g < 2; g++)
            #pragma unroll
            for (int r = 0; r < 4; r++) rs[g][r] += __shfl_xor(rs[g][r], off);

    #pragma unroll
    for (int g = 0; g < 2; g++) {
        u16* Pob = Po + ((long)(split * 8 + bh) * 2048 + q0 + g * 16) * 96;
        #pragma unroll
        for (int nt = 0; nt < 6; nt++)
            #pragma unroll
            for (int r = 0; r < 4; r++)
                Pob[(long)(quad * 4 + r) * 96 + nt * 16 + l15] = f2bf(o[g][nt][r]);
        if (l15 == 0) {
            long mb = (long)(split * 8 + bh) * 2048 + q0 + g * 16 + quad * 4;
            #pragma unroll
            for (int r = 0; r < 4; r++) Pl[mb + r] = rs[g][r];
        }
    }
}

// ---------------- combine 4 key-split partials (bf16) -> Z (bf16, gate/l applied) ----------------
__global__ __launch_bounds__(256)
void attn_combine(const u16* __restrict__ Po, const float* __restrict__ Pl,
                  const float* __restrict__ gates, u16* __restrict__ Z) {
    int bh = blockIdx.y, b = bh >> 2, h = bh & 3;
    int tid = threadIdx.x;
    int rl = tid >> 2, part = tid & 3;
    int row = blockIdx.x * 64 + rl;
    long rbase = (long)bh * 2048 + row;

    float L = 0.f;
    #pragma unroll
    for (int s = 0; s < SPL; s++) L += Pl[s * 16384 + rbase];
    float g = gates ? gates[bh] : 1.f;
    float sc = g / L;

    u16* Zr = Z + ((long)(b * 2048) + row) * 384 + h * 96 + part * 24;
    #pragma unroll
    for (int i = 0; i < 24; i += 4) {
        f32x4 acc = (f32x4){0.f, 0.f, 0.f, 0.f};
        #pragma unroll
        for (int s = 0; s < SPL; s++) {
            u16x4 v = *(const u16x4*)(Po + ((long)s * 16384 + rbase) * 96 + part * 24 + i);
            #pragma unroll
            for (int e = 0; e < 4; e++) acc[e] += bf2f(v[e]);
        }
        u16x4 ov;
        #pragma unroll
        for (int e = 0; e < 4; e++) ov[e] = f2bf(acc[e] * sc);
        *(u16x4*)(Zr + i) = ov;
    }
}

// ---------------- Launch ----------------
extern "C" void kernel_launch(void* const* d_in, const int* in_sizes, int n_in,
                              void* d_out, int out_size, void* d_ws, size_t ws_size,
                              hipStream_t stream) {
    const float* x    = (const float*)d_in[0];
    const float* mem  = (const float*)d_in[1];
    const float* mc   = (const float*)d_in[2];
    const int*   aidx = (const int*)d_in[3];
    const float* cWq = (const float*)d_in[4],  *cbq = (const float*)d_in[5];
    const float* cWk = (const float*)d_in[6],  *cbk = (const float*)d_in[7];
    const float* cWv = (const float*)d_in[8],  *cbv = (const float*)d_in[9];
    const float* cWo = (const float*)d_in[10], *cbo = (const float*)d_in[11];
    const float* sWq = (const float*)d_in[12], *sbq = (const float*)d_in[13];
    const float* sWk = (const float*)d_in[14], *sbk = (const float*)d_in[15];
    const float* sWv = (const float*)d_in[16], *sbv = (const float*)d_in[17];
    const float* sWo = (const float*)d_in[18], *sbo = (const float*)d_in[19];
    const float* gW  = (const float*)d_in[20], *gb  = (const float*)d_in[21];
    const float* f1W = (const float*)d_in[22], *f1b = (const float*)d_in[23];
    const float* f2W = (const float*)d_in[24], *f2b = (const float*)d_in[25];
    const float* adA = (const float*)d_in[26], *adB = (const float*)d_in[27];
    const float* ln1g = (const float*)d_in[28], *ln1b = (const float*)d_in[29];
    const float* ln2g = (const float*)d_in[30], *ln2b = (const float*)d_in[31];
    const float* ln3g = (const float*)d_in[32], *ln3b = (const float*)d_in[33];

    // ---- workspace layout ----
    u16* p = (u16*)d_ws;
    u16* H      = p; p += (size_t)NR_ * 384;
    u16* bufQKV = p; p += (size_t)NR_ * 1152;
    u16* Vt     = p; p += (size_t)B_ * 384 * 2048;
    u16* Zb     = p; p += (size_t)NR_ * 384;
    u16* F      = p; p += (size_t)NR_ * 1536;
    u16* Tl     = p; p += (size_t)NR_ * 16;
    u16* memb   = p; p += (size_t)NR_ * 384;
    u16* Wqkv_c = p; p += 442368;
    u16* Wco    = p; p += 147456;
    u16* Wqkv_s = p; p += 442368;
    u16* Wso    = p; p += 147456;
    u16* Wf1    = p; p += 589824;
    u16* Wf2    = p; p += 589824;
    u16* WadA   = p; p += 24576;
    u16* WadB   = p; p += 24576;
    u16* Po     = p; p += (size_t)SPL * 8 * 2048 * 96;
    float* fp = (float*)(((size_t)p + 3) & ~(size_t)3);
    float* X1 = fp;     fp += (size_t)NR_ * 384;
    float* X2 = fp;     fp += (size_t)NR_ * 384;
    float* Pl = fp;     fp += (size_t)SPL * 8 * 2048;
    float* bqkv_c = fp; fp += 1152;
    float* bqkv_s = fp; fp += 1152;
    float* gbuf   = fp; fp += 8;

    // ---- fused setup ----
    setup_kernel<<<dim3(96, 14), 256, 0, stream>>>(
        cWq, cWk, cWv, cWo, sWq, sWk, sWv, sWo, f1W, f2W, adA, adB, mem,
        Wqkv_c, Wco, Wqkv_s, Wso, Wf1, Wf2, WadA, WadB, memb,
        cbq, cbk, cbv, sbq, sbk, sbv, bqkv_c, bqkv_s, mc, gW, gb, gbuf);

    const float* nf = nullptr;
    const u16* nu = nullptr;
    // --- cross-attention: merged QKV projection (Q from H, K/V from memb) ---
    ln_kernel<<<NR_, 384, 0, stream>>>(x, ln1g, ln1b, H);
    gemm_uni<2, 0, true, true, false, false><<<dim3(18, 64), 256, 0, stream>>>(
        H, memb, 384, Wqkv_c, bqkv_c, nf, bufQKV, 1152, 384, Vt, 768, nu, nu, nullptr, nullptr);
    attn_mfma<<<dim3(16, 8, SPL), 256, 0, stream>>>(bufQKV, 1152, bufQKV + 384, 1152, Vt, Po, Pl);
    attn_combine<<<dim3(32, 8), 256, 0, stream>>>(Po, Pl, nullptr, Zb);
    gemm_uni<1, 0, false, false, false, false><<<dim3(6, 128), 256, 0, stream>>>(
        Zb, Zb, 0, Wco, cbo, x, X1, 384, 384, nullptr, 0, nu, nu, nullptr, nullptr);

    // --- motif-gated self-attention ---
    ln_kernel<<<NR_, 384, 0, stream>>>(X1, ln2g, ln2b, H);
    gemm_uni<2, 0, true, true, false, false><<<dim3(18, 64), 256, 0, stream>>>(
        H, H, 0, Wqkv_s, bqkv_s, nf, bufQKV, 1152, 384, Vt, 768, nu, nu, nullptr, nullptr);
    attn_mfma<<<dim3(16, 8, SPL), 256, 0, stream>>>(bufQKV, 1152, bufQKV + 384, 1152, Vt, Po, Pl);
    attn_combine<<<dim3(32, 8), 256, 0, stream>>>(Po, Pl, gbuf, Zb);
    gemm_uni<1, 0, false, false, false, false><<<dim3(6, 128), 256, 0, stream>>>(
        Zb, Zb, 0, Wso, sbo, X1, X2, 384, 384, nullptr, 0, nu, nu, nullptr, nullptr);

    // --- FFN + LoRA (adA fused into f1 as 25th block-col; loraB fused into f2 epilogue) ---
    ln_kernel<<<NR_, 384, 0, stream>>>(X2, ln3g, ln3b, H);
    gemm_uni<2, 1, true, false, false, true><<<dim3(25, 64), 256, 0, stream>>>(
        H, H, 0, Wf1, f1b, nf, F, 1536, 384, nullptr, 0, nu, WadA, Tl, aidx);
    gemm_uni<1, 0, false, false, true, false><<<dim3(6, 128), 256, 0, stream>>>(
        F, F, 0, Wf2, f2b, X2, d_out, 384, 1536, nullptr, 0, Tl, WadB, nullptr, aidx);
}